// Round 1
// baseline (640.900 us; speedup 1.0000x reference)
//
#include <hip/hip_runtime.h>
#include <hip/hip_bf16.h>

// Problem constants (B=4, L=1024, D=512, H=8, E=64, DIN=1024, N=16, K=4, R=32)
#define BB 4
#define LL 1024
#define DD 512
#define HH 8
#define EE 64
#define DIN 1024
#define NN 16
#define KK 4
#define RR 32
#define BL (BB*LL)   // 4096 rows
#define CC 16        // scan chunks
#define LC (LL/CC)   // 64 steps per chunk
#define BDN (BB*DIN*NN)   // 65536 independent recurrences

using bf16 = __hip_bfloat16;
typedef __attribute__((ext_vector_type(8))) short short8;   // 8 bf16 = 4 VGPRs
typedef __attribute__((ext_vector_type(4))) float f32x4;

__device__ __forceinline__ float ldf(const float* p) { return *p; }
__device__ __forceinline__ float ldf(const bf16* p) { return __bfloat162float(*p); }
__device__ __forceinline__ void stf(float* p, float v) { *p = v; }
__device__ __forceinline__ void stf(bf16* p, float v) { *p = __float2bfloat16(v); }
__device__ __forceinline__ short f2bs(float f) { bf16 h = __float2bfloat16(f); return *(short*)&h; }

// ---------------------------------------------------------------------------
// f32 -> bf16 elementwise convert
// ---------------------------------------------------------------------------
__global__ void cvt_k(const float* __restrict__ in, bf16* __restrict__ out, int n)
{
    int i = blockIdx.x * 256 + threadIdx.x;
    if (i < n) out[i] = __float2bfloat16(in[i]);
}

// ---------------------------------------------------------------------------
// Weight transpose: in f32 [Kd][Nd] row-major -> out bf16 [Nd][Kd] row-major.
// ---------------------------------------------------------------------------
__global__ void tpw_k(const float* __restrict__ in, bf16* __restrict__ outT,
                      int Kd, int Nd)
{
    __shared__ float t[32][33];
    const int n0 = blockIdx.x * 32, k0 = blockIdx.y * 32;
    const int tx = threadIdx.x & 31, ty = threadIdx.x >> 5;
#pragma unroll
    for (int i = 0; i < 4; ++i)
        t[ty + 8 * i][tx] = in[(size_t)(k0 + ty + 8 * i) * Nd + n0 + tx];
    __syncthreads();
#pragma unroll
    for (int i = 0; i < 4; ++i)
        outT[(size_t)(n0 + ty + 8 * i) * Kd + k0 + tx] = __float2bfloat16(t[tx][ty + 8 * i]);
}

// ---------------------------------------------------------------------------
// V transpose per head: vT[bh][e][l] = v[b][l][h*64+e]
// ---------------------------------------------------------------------------
__global__ void tpv_k(const bf16* __restrict__ v, bf16* __restrict__ vT)
{
    __shared__ float t[32][33];
    const int l0 = blockIdx.x * 32;
    const int e0 = blockIdx.y * 32;
    const int bh = blockIdx.z, b = bh >> 3, h = bh & 7;
    const int tx = threadIdx.x & 31, ty = threadIdx.x >> 5;
#pragma unroll
    for (int i = 0; i < 4; ++i)
        t[ty + 8 * i][tx] = ldf(&v[(size_t)(b * LL + l0 + ty + 8 * i) * DD + h * EE + e0 + tx]);
    __syncthreads();
#pragma unroll
    for (int i = 0; i < 4; ++i)
        stf(&vT[(size_t)(bh * EE + e0 + ty + 8 * i) * LL + l0 + tx], t[tx][ty + 8 * i]);
}

// ---------------------------------------------------------------------------
// MFMA GEMM: C[M][N] = A[M][K] @ Bt[N][K]^T (+bias). LDS-free.
// Block 256 = 4 waves 2x2; wave tile 32x32. Grid (N/64, M/64).
// ---------------------------------------------------------------------------
template <typename TC>
__global__ void mfma_gemm_k(const bf16* __restrict__ A, int lda,
                            const bf16* __restrict__ Bt, int ldb,
                            const float* __restrict__ bias,
                            TC* __restrict__ C, int ldc, int Kd)
{
    const int lane = threadIdx.x & 63;
    const int w = threadIdx.x >> 6;
    const int m = lane & 15, quad = lane >> 4;
    const int m0 = blockIdx.y * 64 + (w >> 1) * 32;
    const int n0 = blockIdx.x * 64 + (w & 1) * 32;
    f32x4 acc[2][2] = {};
    const bf16* a0p = A + (size_t)(m0 + m) * lda + quad * 8;
    const bf16* a1p = a0p + (size_t)16 * lda;
    const bf16* b0p = Bt + (size_t)(n0 + m) * ldb + quad * 8;
    const bf16* b1p = b0p + (size_t)16 * ldb;
    for (int k = 0; k < Kd; k += 32) {
        short8 a0 = *(const short8*)(a0p + k);
        short8 a1 = *(const short8*)(a1p + k);
        short8 b0 = *(const short8*)(b0p + k);
        short8 b1 = *(const short8*)(b1p + k);
        acc[0][0] = __builtin_amdgcn_mfma_f32_16x16x32_bf16(a0, b0, acc[0][0], 0, 0, 0);
        acc[0][1] = __builtin_amdgcn_mfma_f32_16x16x32_bf16(a0, b1, acc[0][1], 0, 0, 0);
        acc[1][0] = __builtin_amdgcn_mfma_f32_16x16x32_bf16(a1, b0, acc[1][0], 0, 0, 0);
        acc[1][1] = __builtin_amdgcn_mfma_f32_16x16x32_bf16(a1, b1, acc[1][1], 0, 0, 0);
    }
#pragma unroll
    for (int i = 0; i < 2; ++i)
#pragma unroll
        for (int j = 0; j < 2; ++j)
#pragma unroll
            for (int r = 0; r < 4; ++r) {
                int row = m0 + i * 16 + quad * 4 + r;
                int col = n0 + j * 16 + (lane & 15);
                float vv = acc[i][j][r] + (bias ? bias[col] : 0.f);
                stf(&C[(size_t)row * ldc + col], vv);
            }
}

// ---------------------------------------------------------------------------
// FUSED attention: scores + softmax + (attn@V), one pass.
// Grid (L/16, B*H), block 256 (4 waves).
// Phase A: scores in VGPRs (16 rows x 1024 cols per block; each wave owns a
//   256-col slice), softmax across waves via tiny LDS reductions. Writes the
//   required f32 attn output AND a bf16 copy of P into LDS (A-frag layout
//   conversion happens through LDS: C-layout -> [row][col] -> A-frag reads).
// Phase B: O = P @ V^T-slice. Each wave computes a 16x16 E-slice over the
//   full k=1024 with 32 MFMAs; A-frags from LDS, B-frags from vT (identical
//   indexing to the previously verified attn_av_mfma_k).
// Saves the 128 MB f32 attn re-read from HBM that the separate AV kernel paid.
// ---------------------------------------------------------------------------
__global__ void attn_fused_k(const bf16* __restrict__ q, const bf16* __restrict__ k,
                             const bf16* __restrict__ vT,
                             float* __restrict__ attn, bf16* __restrict__ o)
{
    const int rt = blockIdx.x;
    const int bh = blockIdx.y, b = bh >> 3, h = bh & 7;
    const int w = threadIdx.x >> 6;
    const int lane = threadIdx.x & 63;
    const int m = lane & 15, quad = lane >> 4;
    __shared__ float pm[4][16], ps[4][16];
    // P tile: 16 rows x 1024 cols bf16; row stride 1032 elems = 2064 B
    // (16B-aligned rows for ds_read_b128; stride mod 32 banks = 4 -> ~2-way).
    __shared__ bf16 P[16][1032];

    const bf16* qp = q + (size_t)(b * LL + rt * 16 + m) * DD + h * EE + quad * 8;
    short8 a0 = *(const short8*)(qp);
    short8 a1 = *(const short8*)(qp + 32);

    f32x4 acc[16];
#pragma unroll
    for (int t = 0; t < 16; ++t) {
        int srow = w * 256 + t * 16 + m;
        const bf16* kp = k + (size_t)(b * LL + srow) * DD + h * EE + quad * 8;
        short8 b0 = *(const short8*)(kp);
        short8 b1 = *(const short8*)(kp + 32);
        f32x4 c = {};
        c = __builtin_amdgcn_mfma_f32_16x16x32_bf16(a0, b0, c, 0, 0, 0);
        c = __builtin_amdgcn_mfma_f32_16x16x32_bf16(a1, b1, c, 0, 0, 0);
        acc[t] = c;
    }

#pragma unroll
    for (int r = 0; r < 4; ++r) {
        float mx = -1e30f;
#pragma unroll
        for (int t = 0; t < 16; ++t) { acc[t][r] *= 0.125f; mx = fmaxf(mx, acc[t][r]); }
        mx = fmaxf(mx, __shfl_xor(mx, 1)); mx = fmaxf(mx, __shfl_xor(mx, 2));
        mx = fmaxf(mx, __shfl_xor(mx, 4)); mx = fmaxf(mx, __shfl_xor(mx, 8));
        if (m == 0) pm[w][quad * 4 + r] = mx;
    }
    __syncthreads();
#pragma unroll
    for (int r = 0; r < 4; ++r) {
        float mx = fmaxf(fmaxf(pm[0][quad * 4 + r], pm[1][quad * 4 + r]),
                         fmaxf(pm[2][quad * 4 + r], pm[3][quad * 4 + r]));
        float s = 0.f;
#pragma unroll
        for (int t = 0; t < 16; ++t) { float e = __expf(acc[t][r] - mx); acc[t][r] = e; s += e; }
        s += __shfl_xor(s, 1); s += __shfl_xor(s, 2);
        s += __shfl_xor(s, 4); s += __shfl_xor(s, 8);
        if (m == 0) ps[w][quad * 4 + r] = s;
    }
    __syncthreads();
#pragma unroll
    for (int r = 0; r < 4; ++r) {
        float tot = ps[0][quad * 4 + r] + ps[1][quad * 4 + r] + ps[2][quad * 4 + r] + ps[3][quad * 4 + r];
        float inv = 1.f / tot;
        int row = rt * 16 + quad * 4 + r;
        float* op = attn + ((size_t)bh * LL + row) * LL + w * 256 + (lane & 15);
#pragma unroll
        for (int t = 0; t < 16; ++t) {
            float pv = acc[t][r] * inv;
            op[t * 16] = pv;
            P[quad * 4 + r][w * 256 + t * 16 + m] = __float2bfloat16(pv);
        }
    }
    __syncthreads();

    // Phase B: each wave computes O[16 rows][E-slice w*16..w*16+15].
    const bf16* vp = vT + (size_t)(bh * EE + w * 16 + m) * LL + quad * 8;
    f32x4 oacc = {};
    for (int k0 = 0; k0 < LL; k0 += 32) {
        short8 af = *(const short8*)(&P[m][k0 + quad * 8]);   // A: row m, k=quad*8..+7
        short8 bf = *(const short8*)(vp + k0);                 // B: col m (V^T row)
        oacc = __builtin_amdgcn_mfma_f32_16x16x32_bf16(af, bf, oacc, 0, 0, 0);
    }
#pragma unroll
    for (int r = 0; r < 4; ++r) {
        int row = rt * 16 + quad * 4 + r;
        stf(&o[(size_t)(b * LL + row) * DD + h * EE + w * 16 + (lane & 15)], oacc[r]);
    }
}

// ---------------------------------------------------------------------------
// VALU tiled GEMM (kept for the tiny Wdt GEMM with f32 A).
// ---------------------------------------------------------------------------
template <typename TA, typename TC>
__global__ void gemm_k(const TA* __restrict__ A, int lda,
                       const float* __restrict__ B, int ldb,
                       const float* __restrict__ bias,
                       TC* __restrict__ C, int ldc,
                       int M, int N, int Kd)
{
    __shared__ float As[32][33];
    __shared__ float Bs[32][33];
    const int tid = threadIdx.x;
    const int tx = tid & 31;
    const int ty = tid >> 5;
    const int rowBase = blockIdx.y * 32;
    const int colBase = blockIdx.x * 32;
    float acc[4] = {0.f, 0.f, 0.f, 0.f};

    for (int k0 = 0; k0 < Kd; k0 += 32) {
#pragma unroll
        for (int i = 0; i < 4; ++i) {
            int r = ty + 8 * i;
            As[r][tx] = ldf(&A[(size_t)(rowBase + r) * lda + k0 + tx]);
            Bs[r][tx] = B[(size_t)(k0 + r) * ldb + colBase + tx];
        }
        __syncthreads();
#pragma unroll 8
        for (int kk = 0; kk < 32; ++kk) {
            float bv = Bs[kk][tx];
#pragma unroll
            for (int i = 0; i < 4; ++i) acc[i] += As[ty + 8 * i][kk] * bv;
        }
        __syncthreads();
    }
#pragma unroll
    for (int i = 0; i < 4; ++i) {
        int row = rowBase + ty + 8 * i;
        int col = colBase + tx;
        float r = acc[i] + (bias ? bias[col] : 0.f);
        stf(&C[(size_t)row * ldc + col], r);
    }
}

// ---------------------------------------------------------------------------
// out = LayerNorm(a + r) * g + beta.  One block (256 thr) per row of 512.
// ---------------------------------------------------------------------------
template <typename TA, typename TR, typename TO>
__global__ void add_ln_k(const TA* __restrict__ a, const TR* __restrict__ r,
                         const float* __restrict__ g, const float* __restrict__ be,
                         TO* __restrict__ out)
{
    const int row = blockIdx.x;
    const int tid = threadIdx.x;
    __shared__ float red[256];
    const size_t base = (size_t)row * DD;
    float v0 = ldf(&a[base + tid]) + ldf(&r[base + tid]);
    float v1 = ldf(&a[base + 256 + tid]) + ldf(&r[base + 256 + tid]);
    red[tid] = v0 + v1;
    __syncthreads();
    for (int off = 128; off > 0; off >>= 1) {
        if (tid < off) red[tid] += red[tid + off];
        __syncthreads();
    }
    const float mu = red[0] * (1.f / 512.f);
    __syncthreads();
    float d0 = v0 - mu, d1 = v1 - mu;
    red[tid] = d0 * d0 + d1 * d1;
    __syncthreads();
    for (int off = 128; off > 0; off >>= 1) {
        if (tid < off) red[tid] += red[tid + off];
        __syncthreads();
    }
    const float rs = rsqrtf(red[0] * (1.f / 512.f) + 1e-5f);
    stf(&out[base + tid], d0 * rs * g[tid] + be[tid]);
    stf(&out[base + 256 + tid], d1 * rs * g[tid + 256] + be[tid + 256]);
}

// ---------------------------------------------------------------------------
// Depthwise causal conv (K=4) + bias + SiLU.
// ---------------------------------------------------------------------------
__global__ void conv_silu_k(const bf16* __restrict__ xz,
                            const float* __restrict__ w,
                            const float* __restrict__ cb,
                            bf16* __restrict__ xc)
{
    const int idx = blockIdx.x * 256 + threadIdx.x;
    const int c = idx & (DIN - 1);
    const int t = (idx >> 10) & (LL - 1);
    const int b = idx >> 20;
    float acc = cb[c];
    const bf16* xi = xz + (size_t)b * LL * (2 * DIN) + c;
#pragma unroll
    for (int j = 0; j < KK; ++j) {
        int tt = t - (KK - 1) + j;
        if (tt >= 0) acc += w[c * KK + j] * ldf(&xi[(size_t)tt * (2 * DIN)]);
    }
    stf(&xc[idx], acc / (1.f + __expf(-acc)));
}

__global__ void softplus_k(bf16* __restrict__ p)
{
    const int idx = blockIdx.x * 256 + threadIdx.x;
    float v = ldf(&p[idx]);
    stf(&p[idx], (v > 20.f) ? v : log1pf(__expf(v)));
}

// ---------------------------------------------------------------------------
// Chunked selective scan, phase 1: per (b,d,n,chunk) compute
//   P = prod dA  and  S = chunk-local state starting from h=0.
// Layout P/S: [c][bdn] for coalesced stores/loads. Block 256 = 16d x 16n,
// grid ((DIN/16)*CC, B).
// ---------------------------------------------------------------------------
__global__ void scan_p1_k(const bf16* __restrict__ dt, const bf16* __restrict__ xc,
                          const float* __restrict__ dbl, const float* __restrict__ Alog,
                          float* __restrict__ P, float* __restrict__ S)
{
    const int tid = threadIdx.x;
    const int n = tid & (NN - 1);
    const int dl = tid >> 4;
    const int c = blockIdx.x & (CC - 1);
    const int d = (blockIdx.x >> 4) * 16 + dl;
    const int b = blockIdx.y;
    const float A = -__expf(Alog[d * NN + n]);
    const int t0 = c * LC;
    const bf16* dt_b = dt + ((size_t)b * LL + t0) * DIN + d;
    const bf16* xc_b = xc + ((size_t)b * LL + t0) * DIN + d;
    const float* dbl_b = dbl + ((size_t)b * LL + t0) * 64;
    float Pv = 1.f, Sv = 0.f;
    for (int t = 0; t < LC; ++t) {
        float dtv = ldf(&dt_b[(size_t)t * DIN]);
        float xcv = ldf(&xc_b[(size_t)t * DIN]);
        float Bm = dbl_b[(size_t)t * 64 + RR + n];
        float dA = __expf(dtv * A);
        Sv = Sv * dA + dtv * xcv * Bm;
        Pv *= dA;
    }
    const size_t bdn = ((size_t)(b * DIN + d)) * NN + n;
    P[(size_t)c * BDN + bdn] = Pv;
    S[(size_t)c * BDN + bdn] = Sv;
}

// ---------------------------------------------------------------------------
// Phase 2: serial carry scan over the CC chunks. One thread per bdn.
// Hc[c][bdn] = state entering chunk c.
// ---------------------------------------------------------------------------
__global__ void scan_p2_k(const float* __restrict__ P, const float* __restrict__ S,
                          float* __restrict__ Hc)
{
    const size_t bdn = (size_t)blockIdx.x * 256 + threadIdx.x;
    float h = 0.f;
#pragma unroll
    for (int c = 0; c < CC; ++c) {
        Hc[(size_t)c * BDN + bdn] = h;
        h = S[(size_t)c * BDN + bdn] + P[(size_t)c * BDN + bdn] * h;
    }
}

// ---------------------------------------------------------------------------
// Phase 3: replay each chunk from its carry-in; y = sum_n h*C + xc*D, gated
// by silu(z); y written into the xi half of xz. Same grid as phase 1.
// ---------------------------------------------------------------------------
__global__ void scan_p3_k(const bf16* __restrict__ dt, const bf16* __restrict__ xc,
                          const float* __restrict__ dbl, const float* __restrict__ Alog,
                          const float* __restrict__ Dv, const float* __restrict__ Hc,
                          bf16* __restrict__ xzm)
{
    const int tid = threadIdx.x;
    const int n = tid & (NN - 1);
    const int dl = tid >> 4;
    const int c = blockIdx.x & (CC - 1);
    const int d = (blockIdx.x >> 4) * 16 + dl;
    const int b = blockIdx.y;
    const float A = -__expf(Alog[d * NN + n]);
    const float Dp = Dv[d];
    const int t0 = c * LC;
    const bf16* dt_b = dt + ((size_t)b * LL + t0) * DIN + d;
    const bf16* xc_b = xc + ((size_t)b * LL + t0) * DIN + d;
    const float* dbl_b = dbl + ((size_t)b * LL + t0) * 64;
    bf16* xz_b = xzm + ((size_t)b * LL + t0) * (2 * DIN);
    const size_t bdn = ((size_t)(b * DIN + d)) * NN + n;
    float h = Hc[(size_t)c * BDN + bdn];
    for (int t = 0; t < LC; ++t) {
        float dtv = ldf(&dt_b[(size_t)t * DIN]);
        float xcv = ldf(&xc_b[(size_t)t * DIN]);
        float Bm = dbl_b[(size_t)t * 64 + RR + n];
        float Cm = dbl_b[(size_t)t * 64 + RR + NN + n];
        h = h * __expf(dtv * A) + dtv * xcv * Bm;
        float p = h * Cm;
        p += __shfl_xor(p, 1);
        p += __shfl_xor(p, 2);
        p += __shfl_xor(p, 4);
        p += __shfl_xor(p, 8);
        if (n == 0) {
            float zv = ldf(&xz_b[(size_t)t * (2 * DIN) + DIN + d]);
            float yv = p + xcv * Dp;
            yv *= zv / (1.f + __expf(-zv));
            stf(&xz_b[(size_t)t * (2 * DIN) + d], yv);
        }
    }
}

// ---------------------------------------------------------------------------
extern "C" void kernel_launch(void* const* d_in, const int* in_sizes, int n_in,
                              void* d_out, int out_size, void* d_ws, size_t ws_size,
                              hipStream_t stream)
{
    const float* x    = (const float*)d_in[0];
    const float* Wq   = (const float*)d_in[1];
    const float* bq   = (const float*)d_in[2];
    const float* Wk   = (const float*)d_in[3];
    const float* bk   = (const float*)d_in[4];
    const float* Wv   = (const float*)d_in[5];
    const float* bv   = (const float*)d_in[6];
    const float* Wo   = (const float*)d_in[7];
    const float* bo   = (const float*)d_in[8];
    const float* g1   = (const float*)d_in[9];
    const float* b1   = (const float*)d_in[10];
    const float* g2   = (const float*)d_in[11];
    const float* b2   = (const float*)d_in[12];
    const float* Win  = (const float*)d_in[13];
    const float* cw   = (const float*)d_in[14];
    const float* cb   = (const float*)d_in[15];
    const float* Wx   = (const float*)d_in[16];
    const float* Wdt  = (const float*)d_in[17];
    const float* bdt  = (const float*)d_in[18];
    const float* Alog = (const float*)d_in[19];
    const float* Dv   = (const float*)d_in[20];
    const float* Wout = (const float*)d_in[21];

    float* out  = (float*)d_out;                     // (B,L,D) f32
    float* attn = out + (size_t)BL * DD;             // (B,H,L,L) f32

    const size_t M1 = 1048576;
    bf16* wsb = (bf16*)d_ws;
    bf16* xb   = wsb;                 // 2M bf16 (dead after QKV gemms -> P)
    bf16* q    = wsb + 2*M1;          // 2M (newx; dead after LN1 -> S)
    bf16* kb   = wsb + 4*M1;          // 2M
    bf16* v    = wsb + 6*M1;          // 2M (reused as ym)
    bf16* o    = wsb + 8*M1;          // 2M (dead after Wo gemm -> Hc)
    bf16* x1   = wsb + 10*M1;         // 2M
    bf16* xz   = wsb + 12*M1;         // 8M
    bf16* xc   = wsb + 20*M1;         // 4M
    bf16* dtb  = wsb + 24*M1;         // 4M
    float* dbl = (float*)(wsb + 28*M1);          // 262144 f32
    bf16* vT   = wsb + 28*M1 + 524288;           // 2M
    bf16* Wqt  = vT + 2*M1;
    bf16* Wkt  = Wqt + 262144;
    bf16* Wvt  = Wkt + 262144;
    bf16* Wot  = Wvt + 262144;
    bf16* Wint = Wot + 262144;        // 2048x512 = 1M
    bf16* Wxt  = Wint + M1;           // 64x1024
    bf16* Woutt= Wxt + 65536;         // 512x1024   (end ~69.3 MB)
    bf16* newx = q;
    bf16* ym   = v;
    // Scan scratch aliases dead slots (each needs 4MB = 2M bf16 slots):
    float* Pp = (float*)xb;
    float* Sp = (float*)q;
    float* Hc = (float*)o;

    const dim3 blk(256);

    // Stage 0: converts / transposes
    cvt_k<<<dim3(BL*DD/256), blk, 0, stream>>>(x, xb, BL*DD);
    tpw_k<<<dim3(DD/32, DD/32),  blk, 0, stream>>>(Wq,   Wqt,  DD, DD);
    tpw_k<<<dim3(DD/32, DD/32),  blk, 0, stream>>>(Wk,   Wkt,  DD, DD);
    tpw_k<<<dim3(DD/32, DD/32),  blk, 0, stream>>>(Wv,   Wvt,  DD, DD);
    tpw_k<<<dim3(DD/32, DD/32),  blk, 0, stream>>>(Wo,   Wot,  DD, DD);
    tpw_k<<<dim3(2*DIN/32, DD/32), blk, 0, stream>>>(Win, Wint, DD, 2*DIN);
    tpw_k<<<dim3(64/32, DIN/32), blk, 0, stream>>>(Wx,   Wxt,  DIN, 64);
    tpw_k<<<dim3(DD/32, DIN/32), blk, 0, stream>>>(Wout, Woutt, DIN, DD);

    // QKV projections (MFMA)
    mfma_gemm_k<bf16><<<dim3(DD/64, BL/64), blk, 0, stream>>>(xb, DD, Wqt, DD, bq, q,  DD, DD);
    mfma_gemm_k<bf16><<<dim3(DD/64, BL/64), blk, 0, stream>>>(xb, DD, Wkt, DD, bk, kb, DD, DD);
    mfma_gemm_k<bf16><<<dim3(DD/64, BL/64), blk, 0, stream>>>(xb, DD, Wvt, DD, bv, v,  DD, DD);
    tpv_k<<<dim3(LL/32, EE/32, BB*HH), blk, 0, stream>>>(v, vT);

    // Fused attention: scores + softmax + AV (writes f32 attn output + bf16 o)
    attn_fused_k<<<dim3(LL/16, BB*HH), blk, 0, stream>>>(q, kb, vT, attn, o);

    // Output projection + LN1 (x1 gets its own slot now)
    mfma_gemm_k<bf16><<<dim3(DD/64, BL/64), blk, 0, stream>>>(o, DD, Wot, DD, bo, newx, DD, DD);
    add_ln_k<float, bf16, bf16><<<dim3(BL), blk, 0, stream>>>(x, newx, g1, b1, x1);

    // Mamba in-projection
    mfma_gemm_k<bf16><<<dim3(2*DIN/64, BL/64), blk, 0, stream>>>(x1, DD, Wint, DD, nullptr, xz, 2*DIN, DD);

    // Depthwise conv + SiLU
    conv_silu_k<<<dim3(BL*DIN/256), blk, 0, stream>>>(xz, cw, cb, xc);

    // dbl = xc @ Wx (f32 out)
    mfma_gemm_k<float><<<dim3(64/64, BL/64), blk, 0, stream>>>(xc, DIN, Wxt, DIN, nullptr, dbl, 64, DIN);

    // dt = softplus(dbl[:, :32] @ Wdt + bdt)
    gemm_k<float, bf16><<<dim3(DIN/32, BL/32), blk, 0, stream>>>(dbl, 64, Wdt, DIN, bdt, dtb, DIN, BL, DIN, RR);
    softplus_k<<<dim3(BL*DIN/256), blk, 0, stream>>>(dtb);

    // Chunked selective scan (3 phases) + skip + gate (y -> xi half of xz)
    scan_p1_k<<<dim3((DIN/16)*CC, BB), blk, 0, stream>>>(dtb, xc, dbl, Alog, Pp, Sp);
    scan_p2_k<<<dim3(BDN/256), blk, 0, stream>>>(Pp, Sp, Hc);
    scan_p3_k<<<dim3((DIN/16)*CC, BB), blk, 0, stream>>>(dtb, xc, dbl, Alog, Dv, Hc, xz);

    // Mamba out-projection
    mfma_gemm_k<bf16><<<dim3(DD/64, BL/64), blk, 0, stream>>>(xz, 2*DIN, Woutt, DIN, nullptr, ym, DD, DIN);

    // Final residual LN -> f32 out
    add_ln_k<bf16, bf16, float><<<dim3(BL), blk, 0, stream>>>(x1, ym, g2, b2, out);
}

// Round 5
// 564.918 us; speedup vs baseline: 1.1345x; 1.1345x over previous
//
#include <hip/hip_runtime.h>
#include <hip/hip_bf16.h>

// Problem constants (B=4, L=1024, D=512, H=8, E=64, DIN=1024, N=16, K=4, R=32)
#define BB 4
#define LL 1024
#define DD 512
#define HH 8
#define EE 64
#define DIN 1024
#define NN 16
#define KK 4
#define RR 32
#define BL (BB*LL)   // 4096 rows
#define CC 32        // scan chunks (32 -> LC=32, 2048 waves in p1/p3)
#define LC (LL/CC)   // 32 steps per chunk
#define BDN (BB*DIN*NN)   // 65536 independent recurrences

using bf16 = __hip_bfloat16;
typedef __attribute__((ext_vector_type(8))) short short8;   // 8 bf16 = 4 VGPRs
typedef __attribute__((ext_vector_type(4))) float f32x4;

__device__ __forceinline__ float ldf(const float* p) { return *p; }
__device__ __forceinline__ float ldf(const bf16* p) { return __bfloat162float(*p); }
__device__ __forceinline__ void stf(float* p, float v) { *p = v; }
__device__ __forceinline__ void stf(bf16* p, float v) { *p = __float2bfloat16(v); }
__device__ __forceinline__ short f2bs(float f) { bf16 h = __float2bfloat16(f); return *(short*)&h; }

// ---------------------------------------------------------------------------
// f32 -> bf16 elementwise convert
// ---------------------------------------------------------------------------
__global__ void cvt_k(const float* __restrict__ in, bf16* __restrict__ out, int n)
{
    int i = blockIdx.x * 256 + threadIdx.x;
    if (i < n) out[i] = __float2bfloat16(in[i]);
}

// ---------------------------------------------------------------------------
// Weight transpose: in f32 [Kd][Nd] row-major -> out bf16 [Nd][Kd] row-major.
// ---------------------------------------------------------------------------
__global__ void tpw_k(const float* __restrict__ in, bf16* __restrict__ outT,
                      int Kd, int Nd)
{
    __shared__ float t[32][33];
    const int n0 = blockIdx.x * 32, k0 = blockIdx.y * 32;
    const int tx = threadIdx.x & 31, ty = threadIdx.x >> 5;
#pragma unroll
    for (int i = 0; i < 4; ++i)
        t[ty + 8 * i][tx] = in[(size_t)(k0 + ty + 8 * i) * Nd + n0 + tx];
    __syncthreads();
#pragma unroll
    for (int i = 0; i < 4; ++i)
        outT[(size_t)(n0 + ty + 8 * i) * Kd + k0 + tx] = __float2bfloat16(t[tx][ty + 8 * i]);
}

// ---------------------------------------------------------------------------
// V transpose per head: vT[bh][e][l] = v[b][l][h*64+e]
// ---------------------------------------------------------------------------
__global__ void tpv_k(const bf16* __restrict__ v, bf16* __restrict__ vT)
{
    __shared__ float t[32][33];
    const int l0 = blockIdx.x * 32;
    const int e0 = blockIdx.y * 32;
    const int bh = blockIdx.z, b = bh >> 3, h = bh & 7;
    const int tx = threadIdx.x & 31, ty = threadIdx.x >> 5;
#pragma unroll
    for (int i = 0; i < 4; ++i)
        t[ty + 8 * i][tx] = ldf(&v[(size_t)(b * LL + l0 + ty + 8 * i) * DD + h * EE + e0 + tx]);
    __syncthreads();
#pragma unroll
    for (int i = 0; i < 4; ++i)
        stf(&vT[(size_t)(bh * EE + e0 + ty + 8 * i) * LL + l0 + tx], t[tx][ty + 8 * i]);
}

// ---------------------------------------------------------------------------
// MFMA GEMM: C[M][N] = A[M][K] @ Bt[N][K]^T (+bias). LDS-free.
// Block 256 = 4 waves 2x2; wave tile 32x32. Grid (N/64, M/64).
// ---------------------------------------------------------------------------
template <typename TC>
__global__ void mfma_gemm_k(const bf16* __restrict__ A, int lda,
                            const bf16* __restrict__ Bt, int ldb,
                            const float* __restrict__ bias,
                            TC* __restrict__ C, int ldc, int Kd)
{
    const int lane = threadIdx.x & 63;
    const int w = threadIdx.x >> 6;
    const int m = lane & 15, quad = lane >> 4;
    const int m0 = blockIdx.y * 64 + (w >> 1) * 32;
    const int n0 = blockIdx.x * 64 + (w & 1) * 32;
    f32x4 acc[2][2] = {};
    const bf16* a0p = A + (size_t)(m0 + m) * lda + quad * 8;
    const bf16* a1p = a0p + (size_t)16 * lda;
    const bf16* b0p = Bt + (size_t)(n0 + m) * ldb + quad * 8;
    const bf16* b1p = b0p + (size_t)16 * ldb;
    for (int k = 0; k < Kd; k += 32) {
        short8 a0 = *(const short8*)(a0p + k);
        short8 a1 = *(const short8*)(a1p + k);
        short8 b0 = *(const short8*)(b0p + k);
        short8 b1 = *(const short8*)(b1p + k);
        acc[0][0] = __builtin_amdgcn_mfma_f32_16x16x32_bf16(a0, b0, acc[0][0], 0, 0, 0);
        acc[0][1] = __builtin_amdgcn_mfma_f32_16x16x32_bf16(a0, b1, acc[0][1], 0, 0, 0);
        acc[1][0] = __builtin_amdgcn_mfma_f32_16x16x32_bf16(a1, b0, acc[1][0], 0, 0, 0);
        acc[1][1] = __builtin_amdgcn_mfma_f32_16x16x32_bf16(a1, b1, acc[1][1], 0, 0, 0);
    }
#pragma unroll
    for (int i = 0; i < 2; ++i)
#pragma unroll
        for (int j = 0; j < 2; ++j)
#pragma unroll
            for (int r = 0; r < 4; ++r) {
                int row = m0 + i * 16 + quad * 4 + r;
                int col = n0 + j * 16 + (lane & 15);
                float vv = acc[i][j][r] + (bias ? bias[col] : 0.f);
                stf(&C[(size_t)row * ldc + col], vv);
            }
}

// ---------------------------------------------------------------------------
// FUSED attention: scores + softmax + (attn@V), one pass.
// Grid (L/16, B*H), block 256 (4 waves).
// ---------------------------------------------------------------------------
__global__ void attn_fused_k(const bf16* __restrict__ q, const bf16* __restrict__ k,
                             const bf16* __restrict__ vT,
                             float* __restrict__ attn, bf16* __restrict__ o)
{
    const int rt = blockIdx.x;
    const int bh = blockIdx.y, b = bh >> 3, h = bh & 7;
    const int w = threadIdx.x >> 6;
    const int lane = threadIdx.x & 63;
    const int m = lane & 15, quad = lane >> 4;
    __shared__ float pm[4][16], ps[4][16];
    // P tile: 16 rows x 1024 cols bf16; row stride 1032 elems = 2064 B
    // (16B-aligned rows for ds_read_b128; stride mod 32 banks = 4 -> ~2-way).
    __shared__ bf16 P[16][1032];

    const bf16* qp = q + (size_t)(b * LL + rt * 16 + m) * DD + h * EE + quad * 8;
    short8 a0 = *(const short8*)(qp);
    short8 a1 = *(const short8*)(qp + 32);

    f32x4 acc[16];
#pragma unroll
    for (int t = 0; t < 16; ++t) {
        int srow = w * 256 + t * 16 + m;
        const bf16* kp = k + (size_t)(b * LL + srow) * DD + h * EE + quad * 8;
        short8 b0 = *(const short8*)(kp);
        short8 b1 = *(const short8*)(kp + 32);
        f32x4 c = {};
        c = __builtin_amdgcn_mfma_f32_16x16x32_bf16(a0, b0, c, 0, 0, 0);
        c = __builtin_amdgcn_mfma_f32_16x16x32_bf16(a1, b1, c, 0, 0, 0);
        acc[t] = c;
    }

#pragma unroll
    for (int r = 0; r < 4; ++r) {
        float mx = -1e30f;
#pragma unroll
        for (int t = 0; t < 16; ++t) { acc[t][r] *= 0.125f; mx = fmaxf(mx, acc[t][r]); }
        mx = fmaxf(mx, __shfl_xor(mx, 1)); mx = fmaxf(mx, __shfl_xor(mx, 2));
        mx = fmaxf(mx, __shfl_xor(mx, 4)); mx = fmaxf(mx, __shfl_xor(mx, 8));
        if (m == 0) pm[w][quad * 4 + r] = mx;
    }
    __syncthreads();
#pragma unroll
    for (int r = 0; r < 4; ++r) {
        float mx = fmaxf(fmaxf(pm[0][quad * 4 + r], pm[1][quad * 4 + r]),
                         fmaxf(pm[2][quad * 4 + r], pm[3][quad * 4 + r]));
        float s = 0.f;
#pragma unroll
        for (int t = 0; t < 16; ++t) { float e = __expf(acc[t][r] - mx); acc[t][r] = e; s += e; }
        s += __shfl_xor(s, 1); s += __shfl_xor(s, 2);
        s += __shfl_xor(s, 4); s += __shfl_xor(s, 8);
        if (m == 0) ps[w][quad * 4 + r] = s;
    }
    __syncthreads();
#pragma unroll
    for (int r = 0; r < 4; ++r) {
        float tot = ps[0][quad * 4 + r] + ps[1][quad * 4 + r] + ps[2][quad * 4 + r] + ps[3][quad * 4 + r];
        float inv = 1.f / tot;
        int row = rt * 16 + quad * 4 + r;
        float* op = attn + ((size_t)bh * LL + row) * LL + w * 256 + (lane & 15);
#pragma unroll
        for (int t = 0; t < 16; ++t) {
            float pv = acc[t][r] * inv;
            op[t * 16] = pv;
            P[quad * 4 + r][w * 256 + t * 16 + m] = __float2bfloat16(pv);
        }
    }
    __syncthreads();

    // Phase B: each wave computes O[16 rows][E-slice w*16..w*16+15].
    const bf16* vp = vT + (size_t)(bh * EE + w * 16 + m) * LL + quad * 8;
    f32x4 oacc = {};
    for (int k0 = 0; k0 < LL; k0 += 32) {
        short8 af = *(const short8*)(&P[m][k0 + quad * 8]);   // A: row m, k=quad*8..+7
        short8 bf = *(const short8*)(vp + k0);                 // B: col m (V^T row)
        oacc = __builtin_amdgcn_mfma_f32_16x16x32_bf16(af, bf, oacc, 0, 0, 0);
    }
#pragma unroll
    for (int r = 0; r < 4; ++r) {
        int row = rt * 16 + quad * 4 + r;
        stf(&o[(size_t)(b * LL + row) * DD + h * EE + w * 16 + (lane & 15)], oacc[r]);
    }
}

// ---------------------------------------------------------------------------
// VALU tiled GEMM (kept for the tiny Wdt GEMM with f32 A).
// SP=true fuses softplus into the epilogue (used for dt).
// ---------------------------------------------------------------------------
template <typename TA, typename TC, bool SP>
__global__ void gemm_k(const TA* __restrict__ A, int lda,
                       const float* __restrict__ B, int ldb,
                       const float* __restrict__ bias,
                       TC* __restrict__ C, int ldc,
                       int M, int N, int Kd)
{
    __shared__ float As[32][33];
    __shared__ float Bs[32][33];
    const int tid = threadIdx.x;
    const int tx = tid & 31;
    const int ty = tid >> 5;
    const int rowBase = blockIdx.y * 32;
    const int colBase = blockIdx.x * 32;
    float acc[4] = {0.f, 0.f, 0.f, 0.f};

    for (int k0 = 0; k0 < Kd; k0 += 32) {
#pragma unroll
        for (int i = 0; i < 4; ++i) {
            int r = ty + 8 * i;
            As[r][tx] = ldf(&A[(size_t)(rowBase + r) * lda + k0 + tx]);
            Bs[r][tx] = B[(size_t)(k0 + r) * ldb + colBase + tx];
        }
        __syncthreads();
#pragma unroll 8
        for (int kk = 0; kk < 32; ++kk) {
            float bv = Bs[kk][tx];
#pragma unroll
            for (int i = 0; i < 4; ++i) acc[i] += As[ty + 8 * i][kk] * bv;
        }
        __syncthreads();
    }
#pragma unroll
    for (int i = 0; i < 4; ++i) {
        int row = rowBase + ty + 8 * i;
        int col = colBase + tx;
        float r = acc[i] + (bias ? bias[col] : 0.f);
        if (SP) r = (r > 20.f) ? r : log1pf(__expf(r));
        stf(&C[(size_t)row * ldc + col], r);
    }
}

// ---------------------------------------------------------------------------
// out = LayerNorm(a + r) * g + beta.  One block (256 thr) per row of 512.
// ---------------------------------------------------------------------------
template <typename TA, typename TR, typename TO>
__global__ void add_ln_k(const TA* __restrict__ a, const TR* __restrict__ r,
                         const float* __restrict__ g, const float* __restrict__ be,
                         TO* __restrict__ out)
{
    const int row = blockIdx.x;
    const int tid = threadIdx.x;
    __shared__ float red[256];
    const size_t base = (size_t)row * DD;
    float v0 = ldf(&a[base + tid]) + ldf(&r[base + tid]);
    float v1 = ldf(&a[base + 256 + tid]) + ldf(&r[base + 256 + tid]);
    red[tid] = v0 + v1;
    __syncthreads();
    for (int off = 128; off > 0; off >>= 1) {
        if (tid < off) red[tid] += red[tid + off];
        __syncthreads();
    }
    const float mu = red[0] * (1.f / 512.f);
    __syncthreads();
    float d0 = v0 - mu, d1 = v1 - mu;
    red[tid] = d0 * d0 + d1 * d1;
    __syncthreads();
    for (int off = 128; off > 0; off >>= 1) {
        if (tid < off) red[tid] += red[tid + off];
        __syncthreads();
    }
    const float rs = rsqrtf(red[0] * (1.f / 512.f) + 1e-5f);
    stf(&out[base + tid], d0 * rs * g[tid] + be[tid]);
    stf(&out[base + 256 + tid], d1 * rs * g[tid + 256] + be[tid + 256]);
}

// ---------------------------------------------------------------------------
// Depthwise causal conv (K=4) + bias + SiLU.
// ---------------------------------------------------------------------------
__global__ void conv_silu_k(const bf16* __restrict__ xz,
                            const float* __restrict__ w,
                            const float* __restrict__ cb,
                            bf16* __restrict__ xc)
{
    const int idx = blockIdx.x * 256 + threadIdx.x;
    const int c = idx & (DIN - 1);
    const int t = (idx >> 10) & (LL - 1);
    const int b = idx >> 20;
    float acc = cb[c];
    const bf16* xi = xz + (size_t)b * LL * (2 * DIN) + c;
#pragma unroll
    for (int j = 0; j < KK; ++j) {
        int tt = t - (KK - 1) + j;
        if (tt >= 0) acc += w[c * KK + j] * ldf(&xi[(size_t)tt * (2 * DIN)]);
    }
    stf(&xc[idx], acc / (1.f + __expf(-acc)));
}

// ---------------------------------------------------------------------------
// Chunked selective scan, phase 1 (n-in-register): one thread per (b,d,chunk),
// all NN=16 states in VGPRs. dt/xc loads coalesced across d (64 consecutive
// per wave); Bm loads are wave-uniform -> scalar loads. P = prod dA computed
// as exp(A[n]*sum dt) (1 add/step instead of 16 muls). Block 256 covers 256 d
// for one chunk; grid ((DIN/256)*CC, B).
// ---------------------------------------------------------------------------
__global__ void scan_p1_k(const bf16* __restrict__ dt, const bf16* __restrict__ xc,
                          const float* __restrict__ dbl, const float* __restrict__ Alog,
                          float* __restrict__ P, float* __restrict__ S)
{
    const int d = (blockIdx.x & 3) * 256 + threadIdx.x;   // DIN/256 = 4
    const int c = blockIdx.x >> 2;
    const int b = blockIdx.y;
    float A[NN];
#pragma unroll
    for (int n = 0; n < NN; ++n) A[n] = -__expf(Alog[d * NN + n]);
    const int t0 = c * LC;
    const bf16* dt_b = dt + ((size_t)b * LL + t0) * DIN + d;
    const bf16* xc_b = xc + ((size_t)b * LL + t0) * DIN + d;
    const float* dbl_b = dbl + ((size_t)b * LL + t0) * 64 + RR;   // uniform per wave
    float h[NN];
#pragma unroll
    for (int n = 0; n < NN; ++n) h[n] = 0.f;
    float sdt = 0.f;
#pragma unroll 4
    for (int t = 0; t < LC; ++t) {
        float dtv = ldf(&dt_b[(size_t)t * DIN]);
        float xcv = ldf(&xc_b[(size_t)t * DIN]);
        float dtx = dtv * xcv;
        sdt += dtv;
#pragma unroll
        for (int n = 0; n < NN; ++n) {
            float dA = __expf(dtv * A[n]);
            h[n] = h[n] * dA + dtx * dbl_b[(size_t)t * 64 + n];
        }
    }
    float* Pp = P + (size_t)c * BDN + ((size_t)(b * DIN + d)) * NN;
    float* Sp = S + (size_t)c * BDN + ((size_t)(b * DIN + d)) * NN;
#pragma unroll
    for (int n = 0; n < NN; ++n) { Pp[n] = __expf(sdt * A[n]); Sp[n] = h[n]; }
}

// ---------------------------------------------------------------------------
// Phase 2: serial carry scan over the CC chunks. One thread per bdn.
// Hc[c][bdn] = state entering chunk c.
// ---------------------------------------------------------------------------
__global__ void scan_p2_k(const float* __restrict__ P, const float* __restrict__ S,
                          float* __restrict__ Hc)
{
    const size_t bdn = (size_t)blockIdx.x * 256 + threadIdx.x;
    float h = 0.f;
#pragma unroll
    for (int c = 0; c < CC; ++c) {
        Hc[(size_t)c * BDN + bdn] = h;
        h = S[(size_t)c * BDN + bdn] + P[(size_t)c * BDN + bdn] * h;
    }
}

// ---------------------------------------------------------------------------
// Phase 3 (n-in-register): replay each chunk from its carry-in.
// y = sum_n h[n]*Cm[n] is 16 in-register fmas (no shuffles); z load and y
// store fully coalesced across d. Same grid as phase 1.
// ---------------------------------------------------------------------------
__global__ void scan_p3_k(const bf16* __restrict__ dt, const bf16* __restrict__ xc,
                          const float* __restrict__ dbl, const float* __restrict__ Alog,
                          const float* __restrict__ Dv, const float* __restrict__ Hc,
                          bf16* __restrict__ xzm)
{
    const int d = (blockIdx.x & 3) * 256 + threadIdx.x;
    const int c = blockIdx.x >> 2;
    const int b = blockIdx.y;
    float A[NN];
#pragma unroll
    for (int n = 0; n < NN; ++n) A[n] = -__expf(Alog[d * NN + n]);
    const float Dp = Dv[d];
    const int t0 = c * LC;
    const bf16* dt_b = dt + ((size_t)b * LL + t0) * DIN + d;
    const bf16* xc_b = xc + ((size_t)b * LL + t0) * DIN + d;
    const float* dbl_b = dbl + ((size_t)b * LL + t0) * 64 + RR;   // uniform per wave
    bf16* xz_b = xzm + ((size_t)b * LL + t0) * (2 * DIN);
    const float* hp = Hc + (size_t)c * BDN + ((size_t)(b * DIN + d)) * NN;
    float h[NN];
#pragma unroll
    for (int n = 0; n < NN; ++n) h[n] = hp[n];
#pragma unroll 2
    for (int t = 0; t < LC; ++t) {
        float dtv = ldf(&dt_b[(size_t)t * DIN]);
        float xcv = ldf(&xc_b[(size_t)t * DIN]);
        float dtx = dtv * xcv;
        float y = 0.f;
#pragma unroll
        for (int n = 0; n < NN; ++n) {
            float dA = __expf(dtv * A[n]);
            h[n] = h[n] * dA + dtx * dbl_b[(size_t)t * 64 + n];
            y += h[n] * dbl_b[(size_t)t * 64 + NN + n];
        }
        float zv = ldf(&xz_b[(size_t)t * (2 * DIN) + DIN + d]);
        float yv = y + xcv * Dp;
        yv *= zv / (1.f + __expf(-zv));
        stf(&xz_b[(size_t)t * (2 * DIN) + d], yv);
    }
}

// ---------------------------------------------------------------------------
extern "C" void kernel_launch(void* const* d_in, const int* in_sizes, int n_in,
                              void* d_out, int out_size, void* d_ws, size_t ws_size,
                              hipStream_t stream)
{
    const float* x    = (const float*)d_in[0];
    const float* Wq   = (const float*)d_in[1];
    const float* bq   = (const float*)d_in[2];
    const float* Wk   = (const float*)d_in[3];
    const float* bk   = (const float*)d_in[4];
    const float* Wv   = (const float*)d_in[5];
    const float* bv   = (const float*)d_in[6];
    const float* Wo   = (const float*)d_in[7];
    const float* bo   = (const float*)d_in[8];
    const float* g1   = (const float*)d_in[9];
    const float* b1   = (const float*)d_in[10];
    const float* g2   = (const float*)d_in[11];
    const float* b2   = (const float*)d_in[12];
    const float* Win  = (const float*)d_in[13];
    const float* cw   = (const float*)d_in[14];
    const float* cb   = (const float*)d_in[15];
    const float* Wx   = (const float*)d_in[16];
    const float* Wdt  = (const float*)d_in[17];
    const float* bdt  = (const float*)d_in[18];
    const float* Alog = (const float*)d_in[19];
    const float* Dv   = (const float*)d_in[20];
    const float* Wout = (const float*)d_in[21];

    float* out  = (float*)d_out;                     // (B,L,D) f32
    float* attn = out + (size_t)BL * DD;             // (B,H,L,L) f32

    const size_t M1 = 1048576;
    bf16* wsb = (bf16*)d_ws;
    bf16* xb   = wsb;                 // 2M bf16 [0,4MB)   (dead after QKV gemms)
    bf16* q    = wsb + 2*M1;          // 2M [4,8MB)  (newx; dead after LN1)
    bf16* kb   = wsb + 4*M1;          // 2M [8,12MB) (dead after attn)
    bf16* v    = wsb + 6*M1;          // 2M [12,16MB) (dead after tpv; reused as ym late)
    bf16* o    = wsb + 8*M1;          // 2M (dead after Wo gemm)
    bf16* x1   = wsb + 10*M1;         // 2M (LIVE through final LN)
    bf16* xz   = wsb + 12*M1;         // 8M
    bf16* xc   = wsb + 20*M1;         // 4M
    bf16* dtb  = wsb + 24*M1;         // 4M
    float* dbl = (float*)(wsb + 28*M1);          // 262144 f32
    bf16* vT   = wsb + 28*M1 + 524288;           // 2M [~59.8MB, +4MB)
    bf16* Wqt  = vT + 2*M1;
    bf16* Wkt  = Wqt + 262144;
    bf16* Wvt  = Wkt + 262144;
    bf16* Wot  = Wvt + 262144;
    bf16* Wint = Wot + 262144;        // 2048x512 = 1M
    bf16* Wxt  = Wint + M1;           // 64x1024
    bf16* Woutt= Wxt + 65536;         // 512x1024   (end ~69.3 MB)
    bf16* newx = q;
    bf16* ym   = v;
    // Scan scratch (CC=32 -> 8MB each), aliased onto regions dead at scan time:
    float* Pp = (float*)xb;    // spans xb+q   [0, 8MB)
    float* Sp = (float*)kb;    // spans kb+v   [8MB, 16MB)  (ym=v written after p2 done)
    float* Hc = (float*)vT;    // spans vT..Wint (8MB exactly; Wxt/Woutt untouched)

    const dim3 blk(256);

    // Stage 0: converts / transposes
    cvt_k<<<dim3(BL*DD/256), blk, 0, stream>>>(x, xb, BL*DD);
    tpw_k<<<dim3(DD/32, DD/32),  blk, 0, stream>>>(Wq,   Wqt,  DD, DD);
    tpw_k<<<dim3(DD/32, DD/32),  blk, 0, stream>>>(Wk,   Wkt,  DD, DD);
    tpw_k<<<dim3(DD/32, DD/32),  blk, 0, stream>>>(Wv,   Wvt,  DD, DD);
    tpw_k<<<dim3(DD/32, DD/32),  blk, 0, stream>>>(Wo,   Wot,  DD, DD);
    tpw_k<<<dim3(2*DIN/32, DD/32), blk, 0, stream>>>(Win, Wint, DD, 2*DIN);
    tpw_k<<<dim3(64/32, DIN/32), blk, 0, stream>>>(Wx,   Wxt,  DIN, 64);
    tpw_k<<<dim3(DD/32, DIN/32), blk, 0, stream>>>(Wout, Woutt, DIN, DD);

    // QKV projections (MFMA)
    mfma_gemm_k<bf16><<<dim3(DD/64, BL/64), blk, 0, stream>>>(xb, DD, Wqt, DD, bq, q,  DD, DD);
    mfma_gemm_k<bf16><<<dim3(DD/64, BL/64), blk, 0, stream>>>(xb, DD, Wkt, DD, bk, kb, DD, DD);
    mfma_gemm_k<bf16><<<dim3(DD/64, BL/64), blk, 0, stream>>>(xb, DD, Wvt, DD, bv, v,  DD, DD);
    tpv_k<<<dim3(LL/32, EE/32, BB*HH), blk, 0, stream>>>(v, vT);

    // Fused attention: scores + softmax + AV (writes f32 attn output + bf16 o)
    attn_fused_k<<<dim3(LL/16, BB*HH), blk, 0, stream>>>(q, kb, vT, attn, o);

    // Output projection + LN1
    mfma_gemm_k<bf16><<<dim3(DD/64, BL/64), blk, 0, stream>>>(o, DD, Wot, DD, bo, newx, DD, DD);
    add_ln_k<float, bf16, bf16><<<dim3(BL), blk, 0, stream>>>(x, newx, g1, b1, x1);

    // Mamba in-projection
    mfma_gemm_k<bf16><<<dim3(2*DIN/64, BL/64), blk, 0, stream>>>(x1, DD, Wint, DD, nullptr, xz, 2*DIN, DD);

    // Depthwise conv + SiLU
    conv_silu_k<<<dim3(BL*DIN/256), blk, 0, stream>>>(xz, cw, cb, xc);

    // dbl = xc @ Wx (f32 out)
    mfma_gemm_k<float><<<dim3(64/64, BL/64), blk, 0, stream>>>(xc, DIN, Wxt, DIN, nullptr, dbl, 64, DIN);

    // dt = softplus(dbl[:, :32] @ Wdt + bdt)  (softplus fused in epilogue)
    gemm_k<float, bf16, true><<<dim3(DIN/32, BL/32), blk, 0, stream>>>(dbl, 64, Wdt, DIN, bdt, dtb, DIN, BL, DIN, RR);

    // Chunked selective scan (3 phases) + skip + gate (y -> xi half of xz)
    scan_p1_k<<<dim3((DIN/256)*CC, BB), blk, 0, stream>>>(dtb, xc, dbl, Alog, Pp, Sp);
    scan_p2_k<<<dim3(BDN/256), blk, 0, stream>>>(Pp, Sp, Hc);
    scan_p3_k<<<dim3((DIN/256)*CC, BB), blk, 0, stream>>>(dtb, xc, dbl, Alog, Dv, Hc, xz);

    // Mamba out-projection
    mfma_gemm_k<bf16><<<dim3(DD/64, BL/64), blk, 0, stream>>>(xz, 2*DIN, Woutt, DIN, nullptr, ym, DD, DIN);

    // Final residual LN -> f32 out
    add_ln_k<bf16, bf16, float><<<dim3(BL), blk, 0, stream>>>(x1, ym, g2, b2, out);
}

// Round 6
// 517.475 us; speedup vs baseline: 1.2385x; 1.0917x over previous
//
#include <hip/hip_runtime.h>
#include <hip/hip_bf16.h>

// Problem constants (B=4, L=1024, D=512, H=8, E=64, DIN=1024, N=16, K=4, R=32)
#define BB 4
#define LL 1024
#define DD 512
#define HH 8
#define EE 64
#define DIN 1024
#define NN 16
#define KK 4
#define RR 32
#define BL (BB*LL)   // 4096 rows
#define CC 32        // scan chunks (32 -> LC=32, 2048 waves in p1/p3)
#define LC (LL/CC)   // 32 steps per chunk
#define BDN (BB*DIN*NN)   // 65536 independent recurrences

using bf16 = __hip_bfloat16;
typedef __attribute__((ext_vector_type(8))) short short8;   // 8 bf16 = 4 VGPRs
typedef __attribute__((ext_vector_type(4))) float f32x4;

__device__ __forceinline__ float ldf(const float* p) { return *p; }
__device__ __forceinline__ float ldf(const bf16* p) { return __bfloat162float(*p); }
__device__ __forceinline__ void stf(float* p, float v) { *p = v; }
__device__ __forceinline__ void stf(bf16* p, float v) { *p = __float2bfloat16(v); }

// ---------------------------------------------------------------------------
// f32 -> bf16 elementwise convert
// ---------------------------------------------------------------------------
__global__ void cvt_k(const float* __restrict__ in, bf16* __restrict__ out, int n)
{
    int i = blockIdx.x * 256 + threadIdx.x;
    if (i < n) out[i] = __float2bfloat16(in[i]);
}

// ---------------------------------------------------------------------------
// Batched weight transpose: 7 weights in one launch. Each 32x32 tile is one
// block; a small job table maps blockIdx.x -> (weight, tile).
// in f32 [Kd][Nd] row-major -> out bf16 [Nd][Kd] row-major.
// ---------------------------------------------------------------------------
struct TpwJob { const float* in; bf16* out; int Kd, Nd, gx, tile0; };
struct TpwJobs { TpwJob j[7]; };

__global__ void tpw_batch_k(TpwJobs jobs)
{
    const int tile = blockIdx.x;
    int ji = 0;
#pragma unroll
    for (int i = 1; i < 7; ++i) if (tile >= jobs.j[i].tile0) ji = i;
    const TpwJob jb = jobs.j[ji];
    const int lt = tile - jb.tile0;
    const int n0 = (lt % jb.gx) * 32;
    const int k0 = (lt / jb.gx) * 32;

    __shared__ float t[32][33];
    const int tx = threadIdx.x & 31, ty = threadIdx.x >> 5;
#pragma unroll
    for (int i = 0; i < 4; ++i)
        t[ty + 8 * i][tx] = jb.in[(size_t)(k0 + ty + 8 * i) * jb.Nd + n0 + tx];
    __syncthreads();
#pragma unroll
    for (int i = 0; i < 4; ++i)
        jb.out[(size_t)(n0 + ty + 8 * i) * jb.Kd + k0 + tx] = __float2bfloat16(t[tx][ty + 8 * i]);
}

// ---------------------------------------------------------------------------
// V transpose per head: vT[bh][e][l] = v[b][l][h*64+e]
// ---------------------------------------------------------------------------
__global__ void tpv_k(const bf16* __restrict__ v, bf16* __restrict__ vT)
{
    __shared__ float t[32][33];
    const int l0 = blockIdx.x * 32;
    const int e0 = blockIdx.y * 32;
    const int bh = blockIdx.z, b = bh >> 3, h = bh & 7;
    const int tx = threadIdx.x & 31, ty = threadIdx.x >> 5;
#pragma unroll
    for (int i = 0; i < 4; ++i)
        t[ty + 8 * i][tx] = ldf(&v[(size_t)(b * LL + l0 + ty + 8 * i) * DD + h * EE + e0 + tx]);
    __syncthreads();
#pragma unroll
    for (int i = 0; i < 4; ++i)
        stf(&vT[(size_t)(bh * EE + e0 + ty + 8 * i) * LL + l0 + tx], t[tx][ty + 8 * i]);
}

// ---------------------------------------------------------------------------
// Big MFMA GEMM: 128x128 block tile, 4 waves 2x2, 64x64 per wave (acc[4][4]).
// Per K-step: 8 loads feed 16 MFMAs (2x the load intensity of the 32x32-tile
// version). Optional z-batching: Bt/C advance by bstride/cstride per z, bias
// selected from {bias0,bias1,bias2}. C[M][N] = A[M][K] @ Bt[N][K]^T (+bias).
// Grid (N/128, M/128, nz).
// ---------------------------------------------------------------------------
template <typename TC>
__global__ void mfma_gemm128_k(const bf16* __restrict__ A, int lda,
                               const bf16* __restrict__ Bt0, size_t bstride, int ldb,
                               const float* __restrict__ bias0,
                               const float* __restrict__ bias1,
                               const float* __restrict__ bias2,
                               TC* __restrict__ C0, size_t cstride, int ldc, int Kd)
{
    const int z = blockIdx.z;
    const bf16* Bt = Bt0 + (size_t)z * bstride;
    TC* C = C0 + (size_t)z * cstride;
    const float* bias = (z == 0) ? bias0 : (z == 1) ? bias1 : bias2;

    const int lane = threadIdx.x & 63;
    const int w = threadIdx.x >> 6;
    const int m = lane & 15, quad = lane >> 4;
    const int m0 = blockIdx.y * 128 + (w >> 1) * 64;
    const int n0 = blockIdx.x * 128 + (w & 1) * 64;

    f32x4 acc[4][4] = {};
    const bf16* ap = A + (size_t)(m0 + m) * lda + quad * 8;
    const bf16* bp = Bt + (size_t)(n0 + m) * ldb + quad * 8;
    const size_t rsa = (size_t)16 * lda;
    const size_t rsb = (size_t)16 * ldb;
    for (int k = 0; k < Kd; k += 32) {
        short8 a[4], b[4];
#pragma unroll
        for (int i = 0; i < 4; ++i) a[i] = *(const short8*)(ap + i * rsa + k);
#pragma unroll
        for (int j = 0; j < 4; ++j) b[j] = *(const short8*)(bp + j * rsb + k);
#pragma unroll
        for (int i = 0; i < 4; ++i)
#pragma unroll
            for (int j = 0; j < 4; ++j)
                acc[i][j] = __builtin_amdgcn_mfma_f32_16x16x32_bf16(a[i], b[j], acc[i][j], 0, 0, 0);
    }
    float bv[4];
#pragma unroll
    for (int j = 0; j < 4; ++j) bv[j] = bias ? bias[n0 + j * 16 + m] : 0.f;
#pragma unroll
    for (int i = 0; i < 4; ++i)
#pragma unroll
        for (int j = 0; j < 4; ++j)
#pragma unroll
            for (int r = 0; r < 4; ++r) {
                int row = m0 + i * 16 + quad * 4 + r;
                int col = n0 + j * 16 + m;
                stf(&C[(size_t)row * ldc + col], acc[i][j][r] + bv[j]);
            }
}

// ---------------------------------------------------------------------------
// MFMA GEMM (small-N variant, 64x64 block): kept for the Wx GEMM (N=64).
// ---------------------------------------------------------------------------
template <typename TC>
__global__ void mfma_gemm_k(const bf16* __restrict__ A, int lda,
                            const bf16* __restrict__ Bt, int ldb,
                            const float* __restrict__ bias,
                            TC* __restrict__ C, int ldc, int Kd)
{
    const int lane = threadIdx.x & 63;
    const int w = threadIdx.x >> 6;
    const int m = lane & 15, quad = lane >> 4;
    const int m0 = blockIdx.y * 64 + (w >> 1) * 32;
    const int n0 = blockIdx.x * 64 + (w & 1) * 32;
    f32x4 acc[2][2] = {};
    const bf16* a0p = A + (size_t)(m0 + m) * lda + quad * 8;
    const bf16* a1p = a0p + (size_t)16 * lda;
    const bf16* b0p = Bt + (size_t)(n0 + m) * ldb + quad * 8;
    const bf16* b1p = b0p + (size_t)16 * ldb;
    for (int k = 0; k < Kd; k += 32) {
        short8 a0 = *(const short8*)(a0p + k);
        short8 a1 = *(const short8*)(a1p + k);
        short8 b0 = *(const short8*)(b0p + k);
        short8 b1 = *(const short8*)(b1p + k);
        acc[0][0] = __builtin_amdgcn_mfma_f32_16x16x32_bf16(a0, b0, acc[0][0], 0, 0, 0);
        acc[0][1] = __builtin_amdgcn_mfma_f32_16x16x32_bf16(a0, b1, acc[0][1], 0, 0, 0);
        acc[1][0] = __builtin_amdgcn_mfma_f32_16x16x32_bf16(a1, b0, acc[1][0], 0, 0, 0);
        acc[1][1] = __builtin_amdgcn_mfma_f32_16x16x32_bf16(a1, b1, acc[1][1], 0, 0, 0);
    }
#pragma unroll
    for (int i = 0; i < 2; ++i)
#pragma unroll
        for (int j = 0; j < 2; ++j)
#pragma unroll
            for (int r = 0; r < 4; ++r) {
                int row = m0 + i * 16 + quad * 4 + r;
                int col = n0 + j * 16 + (lane & 15);
                float vv = acc[i][j][r] + (bias ? bias[col] : 0.f);
                stf(&C[(size_t)row * ldc + col], vv);
            }
}

// ---------------------------------------------------------------------------
// FUSED attention: scores + softmax + (attn@V), one pass.
// Grid (L/16, B*H), block 256 (4 waves).
// ---------------------------------------------------------------------------
__global__ void attn_fused_k(const bf16* __restrict__ q, const bf16* __restrict__ k,
                             const bf16* __restrict__ vT,
                             float* __restrict__ attn, bf16* __restrict__ o)
{
    const int rt = blockIdx.x;
    const int bh = blockIdx.y, b = bh >> 3, h = bh & 7;
    const int w = threadIdx.x >> 6;
    const int lane = threadIdx.x & 63;
    const int m = lane & 15, quad = lane >> 4;
    __shared__ float pm[4][16], ps[4][16];
    // P tile: 16 rows x 1024 cols bf16; row stride 1032 elems = 2064 B
    // (16B-aligned rows for ds_read_b128; stride mod 32 banks = 4 -> ~2-way).
    __shared__ bf16 P[16][1032];

    const bf16* qp = q + (size_t)(b * LL + rt * 16 + m) * DD + h * EE + quad * 8;
    short8 a0 = *(const short8*)(qp);
    short8 a1 = *(const short8*)(qp + 32);

    f32x4 acc[16];
#pragma unroll
    for (int t = 0; t < 16; ++t) {
        int srow = w * 256 + t * 16 + m;
        const bf16* kp = k + (size_t)(b * LL + srow) * DD + h * EE + quad * 8;
        short8 b0 = *(const short8*)(kp);
        short8 b1 = *(const short8*)(kp + 32);
        f32x4 c = {};
        c = __builtin_amdgcn_mfma_f32_16x16x32_bf16(a0, b0, c, 0, 0, 0);
        c = __builtin_amdgcn_mfma_f32_16x16x32_bf16(a1, b1, c, 0, 0, 0);
        acc[t] = c;
    }

#pragma unroll
    for (int r = 0; r < 4; ++r) {
        float mx = -1e30f;
#pragma unroll
        for (int t = 0; t < 16; ++t) { acc[t][r] *= 0.125f; mx = fmaxf(mx, acc[t][r]); }
        mx = fmaxf(mx, __shfl_xor(mx, 1)); mx = fmaxf(mx, __shfl_xor(mx, 2));
        mx = fmaxf(mx, __shfl_xor(mx, 4)); mx = fmaxf(mx, __shfl_xor(mx, 8));
        if (m == 0) pm[w][quad * 4 + r] = mx;
    }
    __syncthreads();
#pragma unroll
    for (int r = 0; r < 4; ++r) {
        float mx = fmaxf(fmaxf(pm[0][quad * 4 + r], pm[1][quad * 4 + r]),
                         fmaxf(pm[2][quad * 4 + r], pm[3][quad * 4 + r]));
        float s = 0.f;
#pragma unroll
        for (int t = 0; t < 16; ++t) { float e = __expf(acc[t][r] - mx); acc[t][r] = e; s += e; }
        s += __shfl_xor(s, 1); s += __shfl_xor(s, 2);
        s += __shfl_xor(s, 4); s += __shfl_xor(s, 8);
        if (m == 0) ps[w][quad * 4 + r] = s;
    }
    __syncthreads();
#pragma unroll
    for (int r = 0; r < 4; ++r) {
        float tot = ps[0][quad * 4 + r] + ps[1][quad * 4 + r] + ps[2][quad * 4 + r] + ps[3][quad * 4 + r];
        float inv = 1.f / tot;
        int row = rt * 16 + quad * 4 + r;
        float* op = attn + ((size_t)bh * LL + row) * LL + w * 256 + (lane & 15);
#pragma unroll
        for (int t = 0; t < 16; ++t) {
            float pv = acc[t][r] * inv;
            op[t * 16] = pv;
            P[quad * 4 + r][w * 256 + t * 16 + m] = __float2bfloat16(pv);
        }
    }
    __syncthreads();

    // Phase B: each wave computes O[16 rows][E-slice w*16..w*16+15].
    const bf16* vp = vT + (size_t)(bh * EE + w * 16 + m) * LL + quad * 8;
    f32x4 oacc = {};
    for (int k0 = 0; k0 < LL; k0 += 32) {
        short8 af = *(const short8*)(&P[m][k0 + quad * 8]);   // A: row m, k=quad*8..+7
        short8 bf = *(const short8*)(vp + k0);                 // B: col m (V^T row)
        oacc = __builtin_amdgcn_mfma_f32_16x16x32_bf16(af, bf, oacc, 0, 0, 0);
    }
#pragma unroll
    for (int r = 0; r < 4; ++r) {
        int row = rt * 16 + quad * 4 + r;
        stf(&o[(size_t)(b * LL + row) * DD + h * EE + w * 16 + (lane & 15)], oacc[r]);
    }
}

// ---------------------------------------------------------------------------
// VALU tiled GEMM (kept for the tiny Wdt GEMM with f32 A).
// SP=true fuses softplus into the epilogue (used for dt).
// ---------------------------------------------------------------------------
template <typename TA, typename TC, bool SP>
__global__ void gemm_k(const TA* __restrict__ A, int lda,
                       const float* __restrict__ B, int ldb,
                       const float* __restrict__ bias,
                       TC* __restrict__ C, int ldc,
                       int M, int N, int Kd)
{
    __shared__ float As[32][33];
    __shared__ float Bs[32][33];
    const int tid = threadIdx.x;
    const int tx = tid & 31;
    const int ty = tid >> 5;
    const int rowBase = blockIdx.y * 32;
    const int colBase = blockIdx.x * 32;
    float acc[4] = {0.f, 0.f, 0.f, 0.f};

    for (int k0 = 0; k0 < Kd; k0 += 32) {
#pragma unroll
        for (int i = 0; i < 4; ++i) {
            int r = ty + 8 * i;
            As[r][tx] = ldf(&A[(size_t)(rowBase + r) * lda + k0 + tx]);
            Bs[r][tx] = B[(size_t)(k0 + r) * ldb + colBase + tx];
        }
        __syncthreads();
#pragma unroll 8
        for (int kk = 0; kk < 32; ++kk) {
            float bv = Bs[kk][tx];
#pragma unroll
            for (int i = 0; i < 4; ++i) acc[i] += As[ty + 8 * i][kk] * bv;
        }
        __syncthreads();
    }
#pragma unroll
    for (int i = 0; i < 4; ++i) {
        int row = rowBase + ty + 8 * i;
        int col = colBase + tx;
        float r = acc[i] + (bias ? bias[col] : 0.f);
        if (SP) r = (r > 20.f) ? r : log1pf(__expf(r));
        stf(&C[(size_t)row * ldc + col], r);
    }
}

// ---------------------------------------------------------------------------
// out = LayerNorm(a + r) * g + beta.  One block (256 thr) per row of 512.
// ---------------------------------------------------------------------------
template <typename TA, typename TR, typename TO>
__global__ void add_ln_k(const TA* __restrict__ a, const TR* __restrict__ r,
                         const float* __restrict__ g, const float* __restrict__ be,
                         TO* __restrict__ out)
{
    const int row = blockIdx.x;
    const int tid = threadIdx.x;
    __shared__ float red[256];
    const size_t base = (size_t)row * DD;
    float v0 = ldf(&a[base + tid]) + ldf(&r[base + tid]);
    float v1 = ldf(&a[base + 256 + tid]) + ldf(&r[base + 256 + tid]);
    red[tid] = v0 + v1;
    __syncthreads();
    for (int off = 128; off > 0; off >>= 1) {
        if (tid < off) red[tid] += red[tid + off];
        __syncthreads();
    }
    const float mu = red[0] * (1.f / 512.f);
    __syncthreads();
    float d0 = v0 - mu, d1 = v1 - mu;
    red[tid] = d0 * d0 + d1 * d1;
    __syncthreads();
    for (int off = 128; off > 0; off >>= 1) {
        if (tid < off) red[tid] += red[tid + off];
        __syncthreads();
    }
    const float rs = rsqrtf(red[0] * (1.f / 512.f) + 1e-5f);
    stf(&out[base + tid], d0 * rs * g[tid] + be[tid]);
    stf(&out[base + 256 + tid], d1 * rs * g[tid + 256] + be[tid + 256]);
}

// ---------------------------------------------------------------------------
// Depthwise causal conv (K=4) + bias + SiLU.
// ---------------------------------------------------------------------------
__global__ void conv_silu_k(const bf16* __restrict__ xz,
                            const float* __restrict__ w,
                            const float* __restrict__ cb,
                            bf16* __restrict__ xc)
{
    const int idx = blockIdx.x * 256 + threadIdx.x;
    const int c = idx & (DIN - 1);
    const int t = (idx >> 10) & (LL - 1);
    const int b = idx >> 20;
    float acc = cb[c];
    const bf16* xi = xz + (size_t)b * LL * (2 * DIN) + c;
#pragma unroll
    for (int j = 0; j < KK; ++j) {
        int tt = t - (KK - 1) + j;
        if (tt >= 0) acc += w[c * KK + j] * ldf(&xi[(size_t)tt * (2 * DIN)]);
    }
    stf(&xc[idx], acc / (1.f + __expf(-acc)));
}

// ---------------------------------------------------------------------------
// Chunked selective scan, phase 1 (n-in-register): one thread per (b,d,chunk),
// all NN=16 states in VGPRs. dt/xc loads coalesced across d; Bm loads are
// wave-uniform -> scalar loads. P = exp(A[n]*sum dt).
// Grid ((DIN/256)*CC, B).
// ---------------------------------------------------------------------------
__global__ void scan_p1_k(const bf16* __restrict__ dt, const bf16* __restrict__ xc,
                          const float* __restrict__ dbl, const float* __restrict__ Alog,
                          float* __restrict__ P, float* __restrict__ S)
{
    const int d = (blockIdx.x & 3) * 256 + threadIdx.x;   // DIN/256 = 4
    const int c = blockIdx.x >> 2;
    const int b = blockIdx.y;
    float A[NN];
#pragma unroll
    for (int n = 0; n < NN; ++n) A[n] = -__expf(Alog[d * NN + n]);
    const int t0 = c * LC;
    const bf16* dt_b = dt + ((size_t)b * LL + t0) * DIN + d;
    const bf16* xc_b = xc + ((size_t)b * LL + t0) * DIN + d;
    const float* dbl_b = dbl + ((size_t)b * LL + t0) * 64 + RR;   // uniform per wave
    float h[NN];
#pragma unroll
    for (int n = 0; n < NN; ++n) h[n] = 0.f;
    float sdt = 0.f;
#pragma unroll 4
    for (int t = 0; t < LC; ++t) {
        float dtv = ldf(&dt_b[(size_t)t * DIN]);
        float xcv = ldf(&xc_b[(size_t)t * DIN]);
        float dtx = dtv * xcv;
        sdt += dtv;
#pragma unroll
        for (int n = 0; n < NN; ++n) {
            float dA = __expf(dtv * A[n]);
            h[n] = h[n] * dA + dtx * dbl_b[(size_t)t * 64 + n];
        }
    }
    float* Pp = P + (size_t)c * BDN + ((size_t)(b * DIN + d)) * NN;
    float* Sp = S + (size_t)c * BDN + ((size_t)(b * DIN + d)) * NN;
#pragma unroll
    for (int n = 0; n < NN; ++n) { Pp[n] = __expf(sdt * A[n]); Sp[n] = h[n]; }
}

// ---------------------------------------------------------------------------
// Phase 2: serial carry scan over the CC chunks. One thread per bdn.
// ---------------------------------------------------------------------------
__global__ void scan_p2_k(const float* __restrict__ P, const float* __restrict__ S,
                          float* __restrict__ Hc)
{
    const size_t bdn = (size_t)blockIdx.x * 256 + threadIdx.x;
    float h = 0.f;
#pragma unroll
    for (int c = 0; c < CC; ++c) {
        Hc[(size_t)c * BDN + bdn] = h;
        h = S[(size_t)c * BDN + bdn] + P[(size_t)c * BDN + bdn] * h;
    }
}

// ---------------------------------------------------------------------------
// Phase 3 (n-in-register): replay each chunk from its carry-in.
// ---------------------------------------------------------------------------
__global__ void scan_p3_k(const bf16* __restrict__ dt, const bf16* __restrict__ xc,
                          const float* __restrict__ dbl, const float* __restrict__ Alog,
                          const float* __restrict__ Dv, const float* __restrict__ Hc,
                          bf16* __restrict__ xzm)
{
    const int d = (blockIdx.x & 3) * 256 + threadIdx.x;
    const int c = blockIdx.x >> 2;
    const int b = blockIdx.y;
    float A[NN];
#pragma unroll
    for (int n = 0; n < NN; ++n) A[n] = -__expf(Alog[d * NN + n]);
    const float Dp = Dv[d];
    const int t0 = c * LC;
    const bf16* dt_b = dt + ((size_t)b * LL + t0) * DIN + d;
    const bf16* xc_b = xc + ((size_t)b * LL + t0) * DIN + d;
    const float* dbl_b = dbl + ((size_t)b * LL + t0) * 64 + RR;   // uniform per wave
    bf16* xz_b = xzm + ((size_t)b * LL + t0) * (2 * DIN);
    const float* hp = Hc + (size_t)c * BDN + ((size_t)(b * DIN + d)) * NN;
    float h[NN];
#pragma unroll
    for (int n = 0; n < NN; ++n) h[n] = hp[n];
#pragma unroll 2
    for (int t = 0; t < LC; ++t) {
        float dtv = ldf(&dt_b[(size_t)t * DIN]);
        float xcv = ldf(&xc_b[(size_t)t * DIN]);
        float dtx = dtv * xcv;
        float y = 0.f;
#pragma unroll
        for (int n = 0; n < NN; ++n) {
            float dA = __expf(dtv * A[n]);
            h[n] = h[n] * dA + dtx * dbl_b[(size_t)t * 64 + n];
            y += h[n] * dbl_b[(size_t)t * 64 + NN + n];
        }
        float zv = ldf(&xz_b[(size_t)t * (2 * DIN) + DIN + d]);
        float yv = y + xcv * Dp;
        yv *= zv / (1.f + __expf(-zv));
        stf(&xz_b[(size_t)t * (2 * DIN) + d], yv);
    }
}

// ---------------------------------------------------------------------------
extern "C" void kernel_launch(void* const* d_in, const int* in_sizes, int n_in,
                              void* d_out, int out_size, void* d_ws, size_t ws_size,
                              hipStream_t stream)
{
    const float* x    = (const float*)d_in[0];
    const float* Wq   = (const float*)d_in[1];
    const float* bq   = (const float*)d_in[2];
    const float* Wk   = (const float*)d_in[3];
    const float* bk   = (const float*)d_in[4];
    const float* Wv   = (const float*)d_in[5];
    const float* bv   = (const float*)d_in[6];
    const float* Wo   = (const float*)d_in[7];
    const float* bo   = (const float*)d_in[8];
    const float* g1   = (const float*)d_in[9];
    const float* b1   = (const float*)d_in[10];
    const float* g2   = (const float*)d_in[11];
    const float* b2   = (const float*)d_in[12];
    const float* Win  = (const float*)d_in[13];
    const float* cw   = (const float*)d_in[14];
    const float* cb   = (const float*)d_in[15];
    const float* Wx   = (const float*)d_in[16];
    const float* Wdt  = (const float*)d_in[17];
    const float* bdt  = (const float*)d_in[18];
    const float* Alog = (const float*)d_in[19];
    const float* Dv   = (const float*)d_in[20];
    const float* Wout = (const float*)d_in[21];

    float* out  = (float*)d_out;                     // (B,L,D) f32
    float* attn = out + (size_t)BL * DD;             // (B,H,L,L) f32

    const size_t M1 = 1048576;
    bf16* wsb = (bf16*)d_ws;
    bf16* xb   = wsb;                 // 2M bf16 [0,4MB)   (dead after QKV gemms)
    bf16* q    = wsb + 2*M1;          // 2M [4,8MB)  (newx; dead after LN1)
    bf16* kb   = wsb + 4*M1;          // 2M [8,12MB) (dead after attn)
    bf16* v    = wsb + 6*M1;          // 2M [12,16MB) (dead after tpv; reused as ym late)
    bf16* o    = wsb + 8*M1;          // 2M (dead after Wo gemm)
    bf16* x1   = wsb + 10*M1;         // 2M (LIVE through final LN)
    bf16* xz   = wsb + 12*M1;         // 8M
    bf16* xc   = wsb + 20*M1;         // 4M
    bf16* dtb  = wsb + 24*M1;         // 4M
    float* dbl = (float*)(wsb + 28*M1);          // 262144 f32
    bf16* vT   = wsb + 28*M1 + 524288;           // 2M [~59.8MB, +4MB)
    bf16* Wqt  = vT + 2*M1;
    bf16* Wkt  = Wqt + 262144;
    bf16* Wvt  = Wkt + 262144;
    bf16* Wot  = Wvt + 262144;
    bf16* Wint = Wot + 262144;        // 2048x512 = 1M
    bf16* Wxt  = Wint + M1;           // 64x1024
    bf16* Woutt= Wxt + 65536;         // 512x1024   (end ~69.3 MB)
    bf16* newx = q;
    bf16* ym   = v;
    // Scan scratch (CC=32 -> 8MB each), aliased onto regions dead at scan time:
    float* Pp = (float*)xb;    // spans xb+q   [0, 8MB)
    float* Sp = (float*)kb;    // spans kb+v   [8MB, 16MB)  (ym=v written after p2 done)
    float* Hc = (float*)vT;    // spans vT..Wint (8MB exactly; Wxt/Woutt untouched)

    const dim3 blk(256);

    // Stage 0: convert + batched weight transposes (one launch for all 7)
    cvt_k<<<dim3(BL*DD/256), blk, 0, stream>>>(x, xb, BL*DD);
    TpwJobs tj;
    int t0 = 0, nj = 0;
    auto addjob = [&](const float* in, bf16* outp, int Kd, int Nd) {
        tj.j[nj] = {in, outp, Kd, Nd, Nd / 32, t0};
        t0 += (Nd / 32) * (Kd / 32);
        ++nj;
    };
    addjob(Wq,   Wqt,   DD,  DD);
    addjob(Wk,   Wkt,   DD,  DD);
    addjob(Wv,   Wvt,   DD,  DD);
    addjob(Wo,   Wot,   DD,  DD);
    addjob(Win,  Wint,  DD,  2*DIN);
    addjob(Wx,   Wxt,   DIN, 64);
    addjob(Wout, Woutt, DIN, DD);
    tpw_batch_k<<<dim3(t0), blk, 0, stream>>>(tj);

    // QKV projections fused into one launch (Wqt/Wkt/Wvt and q/kb/v contiguous)
    mfma_gemm128_k<bf16><<<dim3(DD/128, BL/128, 3), blk, 0, stream>>>(
        xb, DD, Wqt, (size_t)DD*DD, DD, bq, bk, bv, q, (size_t)2*M1, DD, DD);
    tpv_k<<<dim3(LL/32, EE/32, BB*HH), blk, 0, stream>>>(v, vT);

    // Fused attention: scores + softmax + AV (writes f32 attn output + bf16 o)
    attn_fused_k<<<dim3(LL/16, BB*HH), blk, 0, stream>>>(q, kb, vT, attn, o);

    // Output projection + LN1
    mfma_gemm128_k<bf16><<<dim3(DD/128, BL/128, 1), blk, 0, stream>>>(
        o, DD, Wot, 0, DD, bo, nullptr, nullptr, newx, 0, DD, DD);
    add_ln_k<float, bf16, bf16><<<dim3(BL), blk, 0, stream>>>(x, newx, g1, b1, x1);

    // Mamba in-projection
    mfma_gemm128_k<bf16><<<dim3(2*DIN/128, BL/128, 1), blk, 0, stream>>>(
        x1, DD, Wint, 0, DD, nullptr, nullptr, nullptr, xz, 0, 2*DIN, DD);

    // Depthwise conv + SiLU
    conv_silu_k<<<dim3(BL*DIN/256), blk, 0, stream>>>(xz, cw, cb, xc);

    // dbl = xc @ Wx (f32 out, N=64 -> small-tile GEMM)
    mfma_gemm_k<float><<<dim3(64/64, BL/64), blk, 0, stream>>>(xc, DIN, Wxt, DIN, nullptr, dbl, 64, DIN);

    // dt = softplus(dbl[:, :32] @ Wdt + bdt)  (softplus fused in epilogue)
    gemm_k<float, bf16, true><<<dim3(DIN/32, BL/32), blk, 0, stream>>>(dbl, 64, Wdt, DIN, bdt, dtb, DIN, BL, DIN, RR);

    // Chunked selective scan (3 phases) + skip + gate (y -> xi half of xz)
    scan_p1_k<<<dim3((DIN/256)*CC, BB), blk, 0, stream>>>(dtb, xc, dbl, Alog, Pp, Sp);
    scan_p2_k<<<dim3(BDN/256), blk, 0, stream>>>(Pp, Sp, Hc);
    scan_p3_k<<<dim3((DIN/256)*CC, BB), blk, 0, stream>>>(dtb, xc, dbl, Alog, Dv, Hc, xz);

    // Mamba out-projection
    mfma_gemm128_k<bf16><<<dim3(DD/128, BL/128, 1), blk, 0, stream>>>(
        xz, 2*DIN, Woutt, 0, DIN, nullptr, nullptr, nullptr, ym, 0, DD, DIN);

    // Final residual LN -> f32 out
    add_ln_k<bf16, bf16, float><<<dim3(BL), blk, 0, stream>>>(x1, ym, g2, b2, out);
}